// Round 3
// baseline (476.892 us; speedup 1.0000x reference)
//
#include <hip/hip_runtime.h>
#include <hip/hip_bf16.h>

#define Bn 256
#define Tn 200
#define En 100
#define Hn 128
#define Kn 13
#define G4 512          // 4H
#define BT 51200        // B*T

typedef __attribute__((ext_vector_type(8))) __bf16 bf8_t;
typedef __attribute__((ext_vector_type(4))) float f4_t;

__device__ __forceinline__ unsigned short f2bf(float f) {
  unsigned int u = __float_as_uint(f);
  u = (u + 0x7FFFu + ((u >> 16) & 1u)) >> 16;
  return (unsigned short)u;
}
__device__ __forceinline__ float bf2f(unsigned short s) {
  return __uint_as_float(((unsigned int)s) << 16);
}
__device__ __forceinline__ float sigm(float x) { return 1.f / (1.f + __expf(-x)); }

// ---------- lens ----------
__global__ __launch_bounds__(64) void k_lens(const int* __restrict__ text,
                                             int* __restrict__ lens_i,
                                             float* __restrict__ out_lens) {
  int b = blockIdx.x, lane = threadIdx.x;
  int cnt = 0;
  for (int t = lane; t < Tn; t += 64) cnt += (text[b * Tn + t] != 0);
  for (int off = 32; off; off >>= 1) cnt += __shfl_down(cnt, off);
  if (lane == 0) { lens_i[b] = cnt; out_lens[b] = (float)cnt; }
}

// ---------- W -> WT bf16 padded: wt[2][512][128] ----------
__global__ __launch_bounds__(256) void k_wt(const float* __restrict__ Wf,
                                            const float* __restrict__ Wb,
                                            unsigned short* __restrict__ wt) {
  int idx = blockIdx.x * 256 + threadIdx.x;   // 0..131071
  int dir = idx >> 16;
  int rem = idx & 65535;
  int n = rem >> 7, k = rem & 127;
  const float* W = dir ? Wb : Wf;
  float v = (k < En) ? W[k * G4 + n] : 0.f;
  wt[idx] = f2bf(v);
}

// ---------- embedding gather -> bf16 padded x[BT][128] ----------
__global__ __launch_bounds__(256) void k_gather(const int* __restrict__ text,
                                                const float* __restrict__ emb,
                                                unsigned short* __restrict__ xg) {
  int row = blockIdx.x * 128 + (threadIdx.x >> 1);
  int half = threadIdx.x & 1;
  int tok = text[row];
  const float* er = emb + (size_t)tok * En;
  unsigned short* xr = xg + (size_t)row * 128 + half * 64;
  #pragma unroll
  for (int c = 0; c < 64; c += 2) {
    int col = half * 64 + c;
    float v0 = (col < En) ? er[col] : 0.f;
    float v1 = (col + 1 < En) ? er[col + 1] : 0.f;
    unsigned int pk = (unsigned int)f2bf(v0) | ((unsigned int)f2bf(v1) << 16);
    *(unsigned int*)(xr + c) = pk;
  }
}

// ---------- xw = x@W + b  (MFMA bf16, single K-tile=128) ----------
__global__ __launch_bounds__(256) void k_gemm_xw(const unsigned short* __restrict__ xg,
                                                 const unsigned short* __restrict__ wt,
                                                 const float* __restrict__ biasf,
                                                 const float* __restrict__ biasb,
                                                 unsigned short* __restrict__ xwf,
                                                 unsigned short* __restrict__ xwb) {
  __shared__ unsigned short As[128 * 128];
  __shared__ unsigned short Bs[128 * 128];
  int mt = blockIdx.x;              // 0..399
  int dir = blockIdx.y >> 2;        // 0=f,1=b
  int nt = blockIdx.y & 3;          // 0..3 (128-wide N tiles)
  const float* bias = dir ? biasb : biasf;
  unsigned short* out = dir ? xwb : xwf;
  int tid = threadIdx.x;
  const unsigned short* wt_d = wt + (size_t)dir * (G4 * 128);

  #pragma unroll
  for (int it = 0; it < 8; it++) {
    int idx = it * 256 + tid;
    int r = idx >> 4, c = idx & 15;
    bf8_t va = *(const bf8_t*)(xg + ((size_t)mt * 128 + r) * 128 + c * 8);
    bf8_t vb = *(const bf8_t*)(wt_d + ((size_t)nt * 128 + r) * 128 + c * 8);
    int byte = (r * 256 + c * 16) ^ ((r & 7) << 4);
    *(bf8_t*)((char*)As + byte) = va;
    *(bf8_t*)((char*)Bs + byte) = vb;
  }
  __syncthreads();
  int wid = tid >> 6, lane = tid & 63;
  int wm = wid >> 1, wn = wid & 1;
  int lr = lane & 15, lk = lane >> 4;
  f4_t zero = {0.f, 0.f, 0.f, 0.f};
  f4_t acc[4][4];
  #pragma unroll
  for (int m = 0; m < 4; m++)
    #pragma unroll
    for (int n = 0; n < 4; n++) acc[m][n] = zero;
  #pragma unroll
  for (int kk = 0; kk < 4; kk++) {
    bf8_t af[4], bv[4];
    #pragma unroll
    for (int m = 0; m < 4; m++) {
      int r = wm * 64 + m * 16 + lr;
      int byte = (r * 256 + kk * 64 + lk * 16) ^ ((r & 7) << 4);
      af[m] = *(const bf8_t*)((const char*)As + byte);
    }
    #pragma unroll
    for (int n = 0; n < 4; n++) {
      int r = wn * 64 + n * 16 + lr;
      int byte = (r * 256 + kk * 64 + lk * 16) ^ ((r & 7) << 4);
      bv[n] = *(const bf8_t*)((const char*)Bs + byte);
    }
    #pragma unroll
    for (int m = 0; m < 4; m++)
      #pragma unroll
      for (int n = 0; n < 4; n++)
        acc[m][n] = __builtin_amdgcn_mfma_f32_16x16x32_bf16(af[m], bv[n], acc[m][n], 0, 0, 0);
  }
  #pragma unroll
  for (int m = 0; m < 4; m++) {
    int rowl = wm * 64 + m * 16 + lk * 4;
    #pragma unroll
    for (int n = 0; n < 4; n++) {
      int colg = nt * 128 + wn * 64 + n * 16 + lr;
      float bvs = bias[colg];
      #pragma unroll
      for (int q = 0; q < 4; q++) {
        size_t row = (size_t)mt * 128 + rowl + q;
        out[row * G4 + colg] = f2bf(acc[m][n][q] + bvs);
      }
    }
  }
}

// ---------- recurrent scan: 256 blocks (128 fwd + 128 bwd), 2 batch rows each ----------
__global__ __launch_bounds__(512, 2) void k_scan(const float* __restrict__ Uf,
                                                 const float* __restrict__ Ub,
                                                 const unsigned short* __restrict__ xwf,
                                                 const unsigned short* __restrict__ xwb,
                                                 unsigned short* __restrict__ hf,
                                                 unsigned short* __restrict__ hb) {
  int blk = blockIdx.x;
  int dir = blk >> 7;
  int pair = blk & 127;
  const float* U = dir ? Ub : Uf;
  const unsigned short* xw = dir ? xwb : xwf;
  unsigned short* hout = dir ? hb : hf;
  int b0 = pair * 2, b1 = b0 + 1;
  int j = threadIdx.x;
  float u[128];                       // U[:, j] resident in VGPRs for all 200 steps
  #pragma unroll
  for (int k = 0; k < 128; k++) u[k] = U[(size_t)k * G4 + j];
  __shared__ __align__(16) float hbf[2][128];
  __shared__ float zbf[2][512];
  if (j < 128) { hbf[0][j] = 0.f; hbf[1][j] = 0.f; }
  float cst = 0.f;
  int ebs = (j >> 7) & 1, ejj = j & 127;
  const unsigned short* xp0 = xw + (size_t)b0 * Tn * G4 + j;
  const unsigned short* xp1 = xw + (size_t)b1 * Tn * G4 + j;
  unsigned short* hp = hout + (size_t)(ebs ? b1 : b0) * Tn * Hn + ejj;
  int t0 = dir ? (Tn - 1) : 0;
  int dt = dir ? -1 : 1;
  float xn0 = bf2f(xp0[(size_t)t0 * G4]);
  float xn1 = bf2f(xp1[(size_t)t0 * G4]);
  __syncthreads();
  int t = t0;
  for (int tt = 0; tt < Tn; tt++) {
    float z0 = xn0, z1 = xn1;
    int tnext = t + dt;
    if (tt < Tn - 1) {                // prefetch next step's xw
      xn0 = bf2f(xp0[(size_t)tnext * G4]);
      xn1 = bf2f(xp1[(size_t)tnext * G4]);
    }
    #pragma unroll
    for (int k = 0; k < 128; k += 4) {
      float4 h0 = *(const float4*)&hbf[0][k];   // broadcast LDS reads
      float4 h1 = *(const float4*)&hbf[1][k];
      z0 = fmaf(h0.x, u[k], z0);
      z0 = fmaf(h0.y, u[k + 1], z0);
      z0 = fmaf(h0.z, u[k + 2], z0);
      z0 = fmaf(h0.w, u[k + 3], z0);
      z1 = fmaf(h1.x, u[k], z1);
      z1 = fmaf(h1.y, u[k + 1], z1);
      z1 = fmaf(h1.z, u[k + 2], z1);
      z1 = fmaf(h1.w, u[k + 3], z1);
    }
    zbf[0][j] = z0;
    zbf[1][j] = z1;
    __syncthreads();
    if (j < 256) {
      float zi = zbf[ebs][ejj];
      float zf = zbf[ebs][ejj + 128];
      float zg = zbf[ebs][ejj + 256];
      float zo = zbf[ebs][ejj + 384];
      float ig = sigm(zi), fg = sigm(zf);
      float gg = fmaxf(zg, 0.f);
      cst = fmaf(fg, cst, ig * gg);
      float hv = sigm(zo) * fmaxf(cst, 0.f);
      hbf[ebs][ejj] = hv;
      hp[(size_t)t * Hn] = f2bf(hv);
    }
    __syncthreads();
    t = tnext;
  }
}

// ---------- logits = softmax([hf|hb] @ Wd + bd) ----------
__global__ __launch_bounds__(128) void k_logits(const unsigned short* __restrict__ hf,
                                                const unsigned short* __restrict__ hb,
                                                const float* __restrict__ Wd,
                                                const float* __restrict__ bd,
                                                float* __restrict__ out) {
  __shared__ unsigned short hs[128 * 256];   // 64KB, XOR-swizzled rows of 512B
  int tid = threadIdx.x;
  size_t row0 = (size_t)blockIdx.x * 128;
  #pragma unroll
  for (int it = 0; it < 16; it++) {
    int idx = it * 128 + tid;
    int r = idx >> 4, c = idx & 15;
    bf8_t vf = *(const bf8_t*)(hf + (row0 + r) * 128 + c * 8);
    bf8_t vb = *(const bf8_t*)(hb + (row0 + r) * 128 + c * 8);
    int byte = (r * 512 + c * 16) ^ ((r & 7) << 4);
    *(bf8_t*)((char*)hs + byte) = vf;
    int byte2 = (r * 512 + 256 + c * 16) ^ ((r & 7) << 4);
    *(bf8_t*)((char*)hs + byte2) = vb;
  }
  __syncthreads();
  float acc[Kn];
  #pragma unroll
  for (int jj = 0; jj < Kn; jj++) acc[jj] = bd[jj];
  int r = tid;
  #pragma unroll 4
  for (int c = 0; c < 32; c++) {
    int byte = (r * 512 + c * 16) ^ ((r & 7) << 4);
    bf8_t v = *(const bf8_t*)((const char*)hs + byte);
    #pragma unroll
    for (int e = 0; e < 8; e++) {
      float h = (float)v[e];
      int k = c * 8 + e;
      #pragma unroll
      for (int jj = 0; jj < Kn; jj++)
        acc[jj] = fmaf(h, Wd[k * Kn + jj], acc[jj]);   // uniform -> scalar loads
    }
  }
  float m = acc[0];
  #pragma unroll
  for (int jj = 1; jj < Kn; jj++) m = fmaxf(m, acc[jj]);
  float s = 0.f;
  #pragma unroll
  for (int jj = 0; jj < Kn; jj++) { acc[jj] = __expf(acc[jj] - m); s += acc[jj]; }
  float inv = 1.f / s;
  float* op = out + (row0 + r) * Kn;
  #pragma unroll
  for (int jj = 0; jj < Kn; jj++) op[jj] = acc[jj] * inv;
}

// ---------- CRF log-likelihood: one wave per batch row ----------
__global__ __launch_bounds__(64) void k_crf(const float* __restrict__ logits,
                                            const int* __restrict__ labels,
                                            const int* __restrict__ lens_i,
                                            const float* __restrict__ trans,
                                            float* __restrict__ out_ll) {
  int b = blockIdx.x, lane = threadIdx.x;
  int len = lens_i[b];
  const float* lg = logits + (size_t)b * Tn * Kn;
  const int* lab = labels + (size_t)b * Tn;
  // unary + pairwise scores (parallel over t)
  float sc = 0.f;
  for (int t = lane; t < Tn; t += 64) {
    if (t < len) {
      sc += lg[t * Kn + lab[t]];
      if (t >= 1) sc += trans[lab[t - 1] * Kn + lab[t]];
    }
  }
  for (int off = 32; off; off >>= 1) sc += __shfl_down(sc, off);
  // alpha recursion on lanes 0..12
  bool act = lane < Kn;
  int jl = act ? lane : 0;
  float etr[Kn];
  #pragma unroll
  for (int i = 0; i < Kn; i++) etr[i] = __expf(trans[i * Kn + jl]);
  float a = act ? lg[jl] : -INFINITY;
  float lgv = (len > 1) ? lg[Kn + jl] : 0.f;
  for (int t = 1; t < len; t++) {
    float lgn = (t + 1 < len) ? lg[(t + 1) * Kn + jl] : 0.f;   // prefetch
    float m = a;
    for (int off = 8; off; off >>= 1) m = fmaxf(m, __shfl_xor(m, off, 16));
    float ea = __expf(a - m);
    float s = 0.f;
    #pragma unroll
    for (int i = 0; i < Kn; i++) s = fmaf(__shfl(ea, i), etr[i], s);
    float anew = m + __logf(s) + lgv;
    if (act) a = anew;
    lgv = lgn;
  }
  float m2 = a;
  for (int off = 8; off; off >>= 1) m2 = fmaxf(m2, __shfl_xor(m2, off, 16));
  float ea2 = act ? __expf(a - m2) : 0.f;
  float ssum = ea2;
  for (int off = 8; off; off >>= 1) ssum += __shfl_xor(ssum, off, 16);
  float logZ = m2 + __logf(ssum);
  if (lane == 0) out_ll[b] = sc - logZ;
}

extern "C" void kernel_launch(void* const* d_in, const int* in_sizes, int n_in,
                              void* d_out, int out_size, void* d_ws, size_t ws_size,
                              hipStream_t stream) {
  const int* text = (const int*)d_in[0];
  const int* labels = (const int*)d_in[1];
  const float* emb = (const float*)d_in[2];
  const float* Wf = (const float*)d_in[3];
  const float* Uf = (const float*)d_in[4];
  const float* bf_ = (const float*)d_in[5];
  const float* Wb = (const float*)d_in[6];
  const float* Ub = (const float*)d_in[7];
  const float* bb_ = (const float*)d_in[8];
  const float* Wd = (const float*)d_in[9];
  const float* bd = (const float*)d_in[10];
  const float* trans = (const float*)d_in[11];
  (void)in_sizes; (void)n_in; (void)out_size; (void)ws_size;

  float* out = (float*)d_out;
  float* out_logits = out;                       // [BT*K]
  float* out_lens = out + (size_t)BT * Kn;       // [B]
  float* out_ll = out_lens + Bn;                 // [B]

  char* ws = (char*)d_ws;
  size_t o = 0;
  int* lens_i = (int*)(ws + o);                o += 1024;
  unsigned short* wt = (unsigned short*)(ws + o);  o += (size_t)2 * G4 * 128 * 2;
  unsigned short* xg = (unsigned short*)(ws + o);  o += (size_t)BT * 128 * 2;
  unsigned short* xwf = (unsigned short*)(ws + o); o += (size_t)BT * G4 * 2;
  unsigned short* xwb = (unsigned short*)(ws + o); o += (size_t)BT * G4 * 2;
  unsigned short* hfb = (unsigned short*)(ws + o); o += (size_t)BT * Hn * 2;
  unsigned short* hbb = (unsigned short*)(ws + o); o += (size_t)BT * Hn * 2;

  hipLaunchKernelGGL(k_lens, dim3(Bn), dim3(64), 0, stream, text, lens_i, out_lens);
  hipLaunchKernelGGL(k_wt, dim3(512), dim3(256), 0, stream, Wf, Wb, wt);
  hipLaunchKernelGGL(k_gather, dim3(400), dim3(256), 0, stream, text, emb, xg);
  hipLaunchKernelGGL(k_gemm_xw, dim3(400, 8), dim3(256), 0, stream, xg, wt, bf_, bb_, xwf, xwb);
  hipLaunchKernelGGL(k_scan, dim3(256), dim3(512), 0, stream, Uf, Ub, xwf, xwb, hfb, hbb);
  hipLaunchKernelGGL(k_logits, dim3(400), dim3(128), 0, stream, hfb, hbb, Wd, bd, out_logits);
  hipLaunchKernelGGL(k_crf, dim3(Bn), dim3(64), 0, stream, out_logits, labels, lens_i, trans, out_ll);
}